// Round 1
// baseline (85.652 us; speedup 1.0000x reference)
//
#include <hip/hip_runtime.h>

// out[b, k, c, f] = x[b, k*125 + c, f]
// x: (16, 32000, 64) f32; out: (16, 255, 250, 64) f32.
// Each output chunk is a contiguous 250*64 f32 = 64 KB slab of the input
// starting at row k*125. Pure coalesced copy.

#define BATCH 16
#define NUM_OVERLAP 255
#define CHUNK_LEN 250
#define N_FILT 64
#define SIG_LEN 32000
#define CHUNK_ADV 125

__global__ __launch_bounds__(256) void chunk_copy_kernel(
    const float4* __restrict__ in, float4* __restrict__ out) {
    // one block per (b, k) chunk
    const int bk = blockIdx.x;                  // 0 .. BATCH*NUM_OVERLAP-1
    const int b = bk / NUM_OVERLAP;
    const int k = bk - b * NUM_OVERLAP;

    const int CHUNK_F4 = CHUNK_LEN * N_FILT / 4;        // 4000 float4 per chunk
    const int ROW_F4   = N_FILT / 4;                    // 16 float4 per time-row

    const float4* __restrict__ src = in  + (size_t)(b * SIG_LEN + k * CHUNK_ADV) * ROW_F4;
    float4* __restrict__       dst = out + (size_t)bk * CHUNK_F4;

    #pragma unroll 4
    for (int i = threadIdx.x; i < CHUNK_F4; i += 256) {
        dst[i] = src[i];
    }
}

extern "C" void kernel_launch(void* const* d_in, const int* in_sizes, int n_in,
                              void* d_out, int out_size, void* d_ws, size_t ws_size,
                              hipStream_t stream) {
    const float4* in = (const float4*)d_in[0];
    float4* out = (float4*)d_out;
    dim3 grid(BATCH * NUM_OVERLAP);   // 4080 blocks
    dim3 block(256);
    chunk_copy_kernel<<<grid, block, 0, stream>>>(in, out);
}

// Round 3
// 81.750 us; speedup vs baseline: 1.0477x; 1.0477x over previous
//
#include <hip/hip_runtime.h>

// out[b, k, c, f] = x[b, k*125 + c, f]
// x: (16, 32000, 64) f32; out: (16, 255, 250, 64) f32.
//
// Read-once / write-twice formulation: input half-chunk h (rows h*125 ..
// h*125+124, 32 KB contiguous) is the FIRST half of output chunk k=h (h<=254)
// and the SECOND half of output chunk k=h-1 (h>=1). One block per (b,h):
// load each 16B vector once, store to both destinations. HBM read drops to
// the 131 MB unique-input minimum; no cache reuse needed at all.

#define BATCH 16
#define NUM_OVERLAP 255        // output chunks per batch
#define NUM_HALF 256           // 32000 / 125 half-chunks per batch
#define HALF_F4 2000           // 125 rows * 64 filt * 4B / 16B = 2000 vec4
#define CHUNK_F4 4000          // 250 * 64 / 4

typedef float f32x4 __attribute__((ext_vector_type(4)));  // true clang vector
                                                          // (nontemporal-ok)

__global__ __launch_bounds__(256) void halfchunk_copy_kernel(
    const f32x4* __restrict__ in, f32x4* __restrict__ out) {
    const int bh = blockIdx.x;              // 0 .. BATCH*NUM_HALF-1
    const int b = bh >> 8;                  // NUM_HALF == 256
    const int h = bh & (NUM_HALF - 1);

    // source half-chunk: contiguous, = in + bh*2000 vec4
    const f32x4* __restrict__ src = in + (size_t)bh * HALF_F4;

    const bool has1 = (h <= NUM_OVERLAP - 1);   // first half of chunk h
    const bool has2 = (h >= 1);                 // second half of chunk h-1
    f32x4* __restrict__ dst1 = out + (size_t)(b * NUM_OVERLAP + h) * CHUNK_F4;
    f32x4* __restrict__ dst2 = out + (size_t)(b * NUM_OVERLAP + h - 1) * CHUNK_F4 + HALF_F4;

    for (int i = threadIdx.x; i < HALF_F4; i += 256) {
        f32x4 v = __builtin_nontemporal_load(&src[i]);
        if (has1) __builtin_nontemporal_store(v, &dst1[i]);
        if (has2) __builtin_nontemporal_store(v, &dst2[i]);
    }
}

extern "C" void kernel_launch(void* const* d_in, const int* in_sizes, int n_in,
                              void* d_out, int out_size, void* d_ws, size_t ws_size,
                              hipStream_t stream) {
    const f32x4* in = (const f32x4*)d_in[0];
    f32x4* out = (f32x4*)d_out;
    dim3 grid(BATCH * NUM_HALF);   // 4096 blocks
    dim3 block(256);
    halfchunk_copy_kernel<<<grid, block, 0, stream>>>(in, out);
}